// Round 2
// 885.086 us; speedup vs baseline: 1.0782x; 1.0782x over previous
//
#include <hip/hip_runtime.h>
#include <stdint.h>
#include <math.h>

// ---------------- constants ----------------
#define SCALE  0.125f

typedef __bf16 bf16;
typedef __bf16 bf16x8 __attribute__((ext_vector_type(8)));
typedef float  f32x4  __attribute__((ext_vector_type(4)));

__device__ __forceinline__ ushort f2b(float f) {
  union { float f; uint32_t u; } v; v.f = f;
  uint32_t u = v.u;
  return (ushort)((u + 0x7fffu + ((u >> 16) & 1u)) >> 16);
}
__device__ __forceinline__ float b2f(ushort s) {
  union { uint32_t u; float f; } v; v.u = ((uint32_t)s) << 16;
  return v.f;
}
__device__ __forceinline__ void g2l16(const ushort* g, ushort* l) {
  __builtin_amdgcn_global_load_lds(
      (const __attribute__((address_space(1))) void*)g,
      (__attribute__((address_space(3))) void*)l, 16, 0, 0);
}
// A&S 7.1.26 erf, |eps| <= 1.5e-7 (far below bf16 rounding). v_rcp + v_exp.
__device__ __forceinline__ float erf_fast(float x) {
  float ax = fabsf(x);
  float t  = __builtin_amdgcn_rcpf(1.0f + 0.3275911f * ax);
  float p  = t * (0.254829592f + t * (-0.284496736f + t * (1.421413741f +
             t * (-1.453152027f + t * 1.061405429f))));
  float e  = __expf(-ax * ax);
  float r  = 1.0f - p * e;
  return copysignf(r, x);
}

// ---------------- conversion kernels ----------------
// x: (S,B,N,D) f32 -> xb: (S,N,B,D) bf16
__global__ __launch_bounds__(256) void conv_x_kernel(const float* __restrict__ x,
                                                     ushort* __restrict__ xb) {
  int idx = blockIdx.x * 256 + threadIdx.x;
  int d4 = idx & 255;
  int n  = (idx >> 8) & 31;
  int b  = (idx >> 13) & 127;
  int s  = idx >> 20;
  float4 v = *(const float4*)(x + (size_t)(((s*128 + b)*32 + n) << 10) + (d4 << 2));
  ushort4 o;
  o.x = f2b(v.x); o.y = f2b(v.y); o.z = f2b(v.z); o.w = f2b(v.w);
  *(ushort4*)(xb + (size_t)(((s*32 + n)*128 + b) << 10) + (d4 << 2)) = o;
}

__global__ __launch_bounds__(256) void conv_q_kernel(const float* __restrict__ q,
                                                     ushort* __restrict__ qb) {
  int idx = blockIdx.x * 256 + threadIdx.x;
  float4 v = *(const float4*)(q + (size_t)idx * 4);
  ushort4 o;
  o.x = f2b(v.x); o.y = f2b(v.y); o.z = f2b(v.z); o.w = f2b(v.w);
  *(ushort4*)(qb + (size_t)idx * 4) = o;
}

// Wt[r][k] = W[k][srccol(r)] (bf16).
// mode 1 = W1 GLU interleave on 64-row groups: group g6 = r>>6, w = r&63:
//   w<32 -> a col g6*32+w ; w>=32 -> gate col 4096 + g6*32 + (w-32).
__global__ __launch_bounds__(256) void transpose_w_kernel(const float* __restrict__ W,
                                                          ushort* __restrict__ Wt,
                                                          int K, int N, int mode) {
  __shared__ float tile[32][33];
  int rt = blockIdx.x, kt = blockIdx.y;
  int r0 = rt * 32;
  int tx = threadIdx.x & 31, ty = threadIdx.x >> 5;
  int src;
  if (mode == 1) {
    int rp = r0 + tx;
    int g6 = rp >> 6, w = rp & 63;
    src = (w < 32) ? (g6*32 + w) : (4096 + g6*32 + (w - 32));
  } else {
    src = r0 + tx;
  }
  for (int i = ty; i < 32; i += 8)
    tile[i][tx] = W[(size_t)(kt*32 + i) * N + src];
  __syncthreads();
  for (int i = ty; i < 32; i += 8)
    Wt[(size_t)(r0 + i) * K + kt*32 + tx] = f2b(tile[tx][i]);
}

// ---------------- main GEMM: 256x256 tile, 8-phase counted-vmcnt pipeline ----
// bf16 A [MxK] x bf16 Bt [NxK]. 512 threads = 8 waves (2M x 4N); per-wave C =
// 128x64 = 8x4 fragments of 16x16 (mfma_f32_16x16x32_bf16). BK=64.
// LDS: A,B double-buffered K-tiles (2 x 32KB each = 128 KiB, 1 block/CU).
// LDS layout per tile: row r (0..255) = 128B = 8 granules of 16B; granule g of
// row r lives at slot g^(r&7) (bank-conflict-free ds_read_b128). Staged via
// global_load_lds with pre-swizzled per-lane global source (linear LDS dest).
// 16x16x32 fragment: lane (qq=lane>>4, c15=lane&15) reads row c15, k-chunk
// kh*32 + qq*8 -> granule kh*4 + qq  (NOT 2*kh+qq — that is the 32x32x16
// formula; round-1 failure was exactly this).
//
// Pipeline invariants (per wave; STG = 1 global_load_lds instr = 1 vmcnt slot):
//   tile t's A-calls {0,2} + B-calls {0..3} land before t's ph0 (boundary
//   vmcnt(2)); tile t's A-calls {1,3} (issued ph3 of t-1) land before t's ph2
//   (vmcnt(4) at end of ph1). Stage issue order per tile t (into nxt buffers,
//   for tile t+1): ph0:B0,B1  ph1:B2,B3  ph2:A0,A2  ph3:A1,A3.
//   Issue-order is pinned by the memory-clobbered waitcnt asm adjacent to each
//   barrier; loop body contains no other vmem ops, so the counts are exact.
//   Last tile wrap-stages tile 0 (into dead buffers) so counts stay uniform.
// EPI 0: store bf16 -> outb (stride NCOLS)
// EPI 1: in-register GLU (64-group-interleaved W1t) -> hidden bf16 (stride 4096)
// EPI 2: float out = acc + bias[col] + resid (stride NCOLS)
template <int EPI, int K, int NCOLS>
__global__ __launch_bounds__(512, 2) void gemm256(const ushort* __restrict__ A,
                                                  const ushort* __restrict__ Bt,
                                                  float* __restrict__ outf,
                                                  ushort* __restrict__ outb,
                                                  const float* __restrict__ bias,
                                                  const float* __restrict__ resid) {
  __shared__ ushort As[2][16384];
  __shared__ ushort Bs[2][16384];
  constexpr int NT  = K / 64;
  constexpr int nBn = NCOLS / 256;

  // XCD-aware swizzle (all grids are multiples of 8)
  const int nwg = (int)gridDim.x;
  const int bid = (int)blockIdx.x;
  const int wg  = (bid & 7) * (nwg >> 3) + (bid >> 3);
  const int bm = wg / nBn, bn = wg % nBn;

  const int t = threadIdx.x;
  const int wave = t >> 6, lane = t & 63;
  const int wm = wave >> 2, wn = wave & 3;
  const int c15 = lane & 15, qq = lane >> 4;
  const int swz = c15 & 7;

  // staging: thread t -> row (t>>3) within 64-row call block, slot t&7,
  // source granule (t&7)^(row&7)
  const int rowc = t >> 3;
  const int kg = (t & 7) ^ (rowc & 7);
  const ushort* ag = A  + (size_t)(bm*256 + rowc) * K + kg*8;
  const ushort* bg = Bt + (size_t)(bn*256 + rowc) * K + kg*8;

  f32x4 acc[8][4] = {};

#define LDA_F(buf, mi, kh) \
  (*(const bf16x8*)(&As[buf][(wm*128 + (mi)*16 + c15)*64 + ((((kh)*4 + qq) ^ swz)*8)]))
#define LDB_F(buf, ni, kh) \
  (*(const bf16x8*)(&Bs[buf][(wn*64 + (ni)*16 + c15)*64 + ((((kh)*4 + qq) ^ swz)*8)]))
#define STG_A(c, buf, kt) \
  g2l16(ag + (size_t)(c)*64*K + (size_t)(kt)*64, &As[buf][(c)*4096 + wave*512])
#define STG_B(c, buf, kt) \
  g2l16(bg + (size_t)(c)*64*K + (size_t)(kt)*64, &Bs[buf][(c)*4096 + wave*512])

#define MFMA8(p, aa, ab, kh) \
  _Pragma("unroll") \
  for (int ni = 0; ni < 4; ++ni) { \
    acc[2*(p)][ni]   = __builtin_amdgcn_mfma_f32_16x16x32_bf16((aa), bfv[ni][(kh)], acc[2*(p)][ni],   0, 0, 0); \
    acc[2*(p)+1][ni] = __builtin_amdgcn_mfma_f32_16x16x32_bf16((ab), bfv[ni][(kh)], acc[2*(p)+1][ni], 0, 0, 0); \
  }

  // prologue: stage tile 0; order [B0..B3, A0, A2 | A1, A3 left in flight]
  STG_B(0, 0, 0); STG_B(1, 0, 0); STG_B(2, 0, 0); STG_B(3, 0, 0);
  STG_A(0, 0, 0); STG_A(2, 0, 0); STG_A(1, 0, 0); STG_A(3, 0, 0);
  asm volatile("s_waitcnt vmcnt(2)" ::: "memory");
  __builtin_amdgcn_s_barrier();

#define TILE(kt, cur) { \
    const int nx_ = (cur) ^ 1; \
    const int tn_ = ((kt) + 1 == NT) ? 0 : ((kt) + 1); \
    bf16x8 bfv[4][2]; \
    /* ---- phase 0: A frags 0,1 + all B; stage B0,B1(next) ---- */ { \
      bf16x8 a00 = LDA_F(cur, 0, 0), a01 = LDA_F(cur, 0, 1); \
      bf16x8 a10 = LDA_F(cur, 1, 0), a11 = LDA_F(cur, 1, 1); \
      _Pragma("unroll") \
      for (int ni = 0; ni < 4; ++ni) { bfv[ni][0] = LDB_F(cur, ni, 0); bfv[ni][1] = LDB_F(cur, ni, 1); } \
      STG_B(0, nx_, tn_); STG_B(1, nx_, tn_); \
      __builtin_amdgcn_s_barrier(); \
      asm volatile("s_waitcnt lgkmcnt(0)" ::: "memory"); \
      __builtin_amdgcn_sched_barrier(0); \
      __builtin_amdgcn_s_setprio(1); \
      MFMA8(0, a00, a10, 0); MFMA8(0, a01, a11, 1); \
      __builtin_amdgcn_s_setprio(0); \
      __builtin_amdgcn_s_barrier(); \
    } \
    /* ---- phase 1: A frags 2,3; stage B2,B3(next); vmcnt(4) ---- */ { \
      bf16x8 a00 = LDA_F(cur, 2, 0), a01 = LDA_F(cur, 2, 1); \
      bf16x8 a10 = LDA_F(cur, 3, 0), a11 = LDA_F(cur, 3, 1); \
      STG_B(2, nx_, tn_); STG_B(3, nx_, tn_); \
      __builtin_amdgcn_s_barrier(); \
      asm volatile("s_waitcnt lgkmcnt(0)" ::: "memory"); \
      __builtin_amdgcn_sched_barrier(0); \
      __builtin_amdgcn_s_setprio(1); \
      MFMA8(1, a00, a10, 0); MFMA8(1, a01, a11, 1); \
      __builtin_amdgcn_s_setprio(0); \
      asm volatile("s_waitcnt vmcnt(4)" ::: "memory"); \
      __builtin_amdgcn_s_barrier(); \
    } \
    /* ---- phase 2: A frags 4,5; stage A0,A2(next) ---- */ { \
      bf16x8 a00 = LDA_F(cur, 4, 0), a01 = LDA_F(cur, 4, 1); \
      bf16x8 a10 = LDA_F(cur, 5, 0), a11 = LDA_F(cur, 5, 1); \
      STG_A(0, nx_, tn_); STG_A(2, nx_, tn_); \
      __builtin_amdgcn_s_barrier(); \
      asm volatile("s_waitcnt lgkmcnt(0)" ::: "memory"); \
      __builtin_amdgcn_sched_barrier(0); \
      __builtin_amdgcn_s_setprio(1); \
      MFMA8(2, a00, a10, 0); MFMA8(2, a01, a11, 1); \
      __builtin_amdgcn_s_setprio(0); \
      __builtin_amdgcn_s_barrier(); \
    } \
    /* ---- phase 3: A frags 6,7; stage A1,A3(next); vmcnt(2) ---- */ { \
      bf16x8 a00 = LDA_F(cur, 6, 0), a01 = LDA_F(cur, 6, 1); \
      bf16x8 a10 = LDA_F(cur, 7, 0), a11 = LDA_F(cur, 7, 1); \
      STG_A(1, nx_, tn_); STG_A(3, nx_, tn_); \
      __builtin_amdgcn_s_barrier(); \
      asm volatile("s_waitcnt lgkmcnt(0)" ::: "memory"); \
      __builtin_amdgcn_sched_barrier(0); \
      __builtin_amdgcn_s_setprio(1); \
      MFMA8(3, a00, a10, 0); MFMA8(3, a01, a11, 1); \
      __builtin_amdgcn_s_setprio(0); \
      asm volatile("s_waitcnt vmcnt(2)" ::: "memory"); \
      __builtin_amdgcn_s_barrier(); \
    } \
  }

#pragma unroll 1
  for (int kt = 0; kt < NT; kt += 2) {
    TILE(kt, 0);
    TILE(kt + 1, 1);
  }
  // drain wrap-stage DMAs before LDS dealloc at wave exit
  asm volatile("s_waitcnt vmcnt(0)" ::: "memory");

#undef TILE
#undef MFMA8
#undef STG_A
#undef STG_B
#undef LDA_F
#undef LDB_F

  // C/D layout (m89/m91): col = lane&15, row = (lane>>4)*4 + reg
  if (EPI == 0) {
#pragma unroll
    for (int mi = 0; mi < 8; ++mi) {
      int row0 = bm*256 + wm*128 + mi*16 + qq*4;
#pragma unroll
      for (int j = 0; j < 4; ++j) {
#pragma unroll
        for (int ni = 0; ni < 4; ++ni) {
          int col = bn*256 + wn*64 + ni*16 + c15;
          outb[(size_t)(row0 + j) * NCOLS + col] = f2b(acc[mi][ni][j]);
        }
      }
    }
  } else if (EPI == 1) {
    // wave's 64-col slice == one GLU 64-group: g6 = bn*4 + wn.
    // ni 0,1 = 'a' (cols g6*32 + ni*16 + c15); ni 2,3 = gate (same hidden col).
    const int g6 = bn*4 + wn;
    const int hcol0 = g6*32 + c15;
    float ba0 = bias[hcol0],        ba1 = bias[hcol0 + 16];
    float bg0 = bias[4096 + hcol0], bg1 = bias[4096 + hcol0 + 16];
#pragma unroll
    for (int mi = 0; mi < 8; ++mi) {
      int row0 = bm*256 + wm*128 + mi*16 + qq*4;
#pragma unroll
      for (int j = 0; j < 4; ++j) {
        float a0 = acc[mi][0][j] + ba0, g0 = acc[mi][2][j] + bg0;
        float a1 = acc[mi][1][j] + ba1, g1 = acc[mi][3][j] + bg1;
        float ge0 = 0.5f * g0 * (1.0f + erf_fast(g0 * 0.70710678118654752f));
        float ge1 = 0.5f * g1 * (1.0f + erf_fast(g1 * 0.70710678118654752f));
        size_t rb = (size_t)(row0 + j) * 4096;
        outb[rb + hcol0]      = f2b(a0 * ge0);
        outb[rb + hcol0 + 16] = f2b(a1 * ge1);
      }
    }
  } else {
    float bc[4];
#pragma unroll
    for (int ni = 0; ni < 4; ++ni) bc[ni] = bias[bn*256 + wn*64 + ni*16 + c15];
#pragma unroll
    for (int mi = 0; mi < 8; ++mi) {
      int row0 = bm*256 + wm*128 + mi*16 + qq*4;
#pragma unroll
      for (int j = 0; j < 4; ++j) {
#pragma unroll
        for (int ni = 0; ni < 4; ++ni) {
          int col = bn*256 + wn*64 + ni*16 + c15;
          size_t o = (size_t)(row0 + j) * NCOLS + col;
          outf[o] = acc[mi][ni][j] + bc[ni] + resid[o];
        }
      }
    }
  }
}

// ---------------- attention ----------------
__global__ __launch_bounds__(256) void attn_kernel(const ushort* __restrict__ kv,
                                                   const ushort* __restrict__ qb,
                                                   const int* __restrict__ mask,
                                                   float* __restrict__ out) {
  __shared__ ushort Ks[128 * 72];
  __shared__ ushort Vt[64 * 136];
  __shared__ ushort Ps[64 * 136];
  __shared__ float  Mrow[128];

  const int bid = blockIdx.x;
  const int h = bid & 15, n = (bid >> 4) & 31, s = bid >> 9;
  const size_t kvbase = (size_t)((s*32 + n) * 128) * 2048;
  const int t = threadIdx.x, wave = t >> 6, lane = t & 63;
  const int qq = lane >> 4, r = lane & 15;

  if (t < 128) Mrow[t] = (mask[s*128 + t] == 0) ? 1.0f : 0.0f;

  for (int c = t; c < 1024; c += 256) {
    int b = c >> 3, d0 = (c & 7) * 8;
    uint4 v = *(const uint4*)(kv + kvbase + (size_t)b * 2048 + h*64 + d0);
    *(uint4*)(Ks + b*72 + d0) = v;
  }
  {
    int b = t & 127, dh = t >> 7;
    for (int jj = 0; jj < 32; jj += 8) {
      uint4 v = *(const uint4*)(kv + kvbase + (size_t)b * 2048 + 1024 + h*64 + dh*32 + jj);
      const ushort* pv = (const ushort*)&v;
#pragma unroll
      for (int u8 = 0; u8 < 8; u8++)
        Vt[(dh*32 + jj + u8)*136 + b] = pv[u8];
    }
  }
  __syncthreads();

  bf16x8 aq[2];
#pragma unroll
  for (int st = 0; st < 2; st++)
    aq[st] = *(const bf16x8*)(qb + (size_t)(wave*16 + r) * 1024 + h*64 + st*32 + qq*8);
  f32x4 sim[8];
#pragma unroll
  for (int jt = 0; jt < 8; jt++) {
    f32x4 c = {};
#pragma unroll
    for (int st = 0; st < 2; st++) {
      bf16x8 bk = *(const bf16x8*)(Ks + (jt*16 + r)*72 + st*32 + qq*8);
      c = __builtin_amdgcn_mfma_f32_16x16x32_bf16(aq[st], bk, c, 0, 0, 0);
    }
    sim[jt] = c;
  }

#pragma unroll
  for (int jt = 0; jt < 8; jt++) {
    float mflag = Mrow[jt*16 + r];
#pragma unroll
    for (int ii = 0; ii < 4; ii++) {
      float v = sim[jt][ii] * SCALE;
      sim[jt][ii] = (mflag > 0.5f) ? -1e10f : v;
    }
  }
  float mx[4] = {-3.0e38f, -3.0e38f, -3.0e38f, -3.0e38f};
#pragma unroll
  for (int jt = 0; jt < 8; jt++)
#pragma unroll
    for (int ii = 0; ii < 4; ii++) mx[ii] = fmaxf(mx[ii], sim[jt][ii]);
#pragma unroll
  for (int m = 1; m < 16; m <<= 1)
#pragma unroll
    for (int ii = 0; ii < 4; ii++) mx[ii] = fmaxf(mx[ii], __shfl_xor(mx[ii], m));
  float sm[4] = {0.f, 0.f, 0.f, 0.f};
#pragma unroll
  for (int jt = 0; jt < 8; jt++)
#pragma unroll
    for (int ii = 0; ii < 4; ii++) {
      float e = expf(sim[jt][ii] - mx[ii]);
      sim[jt][ii] = e;
      sm[ii] += e;
    }
#pragma unroll
  for (int m = 1; m < 16; m <<= 1)
#pragma unroll
    for (int ii = 0; ii < 4; ii++) sm[ii] += __shfl_xor(sm[ii], m);
#pragma unroll
  for (int ii = 0; ii < 4; ii++) sm[ii] = 1.0f / sm[ii];
#pragma unroll
  for (int jt = 0; jt < 8; jt++)
#pragma unroll
    for (int ii = 0; ii < 4; ii++)
      Ps[(wave*16 + qq*4 + ii)*136 + jt*16 + r] = f2b(sim[jt][ii] * sm[ii]);
  __syncthreads();

  f32x4 o[4] = {};
#pragma unroll
  for (int kst = 0; kst < 4; kst++) {
    bf16x8 ap = *(const bf16x8*)(Ps + (wave*16 + r)*136 + kst*32 + qq*8);
#pragma unroll
    for (int jt2 = 0; jt2 < 4; jt2++) {
      bf16x8 bv = *(const bf16x8*)(Vt + (jt2*16 + r)*136 + kst*32 + qq*8);
      o[jt2] = __builtin_amdgcn_mfma_f32_16x16x32_bf16(ap, bv, o[jt2], 0, 0, 0);
    }
  }
  const size_t orow0 = (size_t)((s*32 + n) * 64);
#pragma unroll
  for (int jt2 = 0; jt2 < 4; jt2++)
#pragma unroll
    for (int ii = 0; ii < 4; ii++) {
      int qr = wave*16 + qq*4 + ii;
      int d  = jt2*16 + r;
      out[(orow0 + qr) * 1024 + h*64 + d] = o[jt2][ii];
    }
}

// ---------------- LayerNorm (in-place) + bf16 copy ----------------
__global__ __launch_bounds__(256) void ln_kernel(float* __restrict__ y,
                                                 ushort* __restrict__ yb,
                                                 const float* __restrict__ g,
                                                 const float* __restrict__ b) {
  __shared__ float r1[4], r2[4];
  const int row = blockIdx.x, t = threadIdx.x;
  const int wave = t >> 6, lane = t & 63;
  float* p = y + (size_t)row * 1024;
  float4 v = *(const float4*)(p + t*4);
  float s1 = v.x + v.y + v.z + v.w;
  float s2 = v.x*v.x + v.y*v.y + v.z*v.z + v.w*v.w;
#pragma unroll
  for (int m = 1; m < 64; m <<= 1) { s1 += __shfl_xor(s1, m); s2 += __shfl_xor(s2, m); }
  if (lane == 0) { r1[wave] = s1; r2[wave] = s2; }
  __syncthreads();
  s1 = r1[0] + r1[1] + r1[2] + r1[3];
  s2 = r2[0] + r2[1] + r2[2] + r2[3];
  float mu  = s1 * (1.0f/1024.0f);
  float var = s2 * (1.0f/1024.0f) - mu*mu;
  float inv = rsqrtf(var + 1e-5f);
  float4 gg = *(const float4*)(g + t*4);
  float4 bb = *(const float4*)(b + t*4);
  float4 o;
  o.x = (v.x - mu)*inv*gg.x + bb.x;
  o.y = (v.y - mu)*inv*gg.y + bb.y;
  o.z = (v.z - mu)*inv*gg.z + bb.z;
  o.w = (v.w - mu)*inv*gg.w + bb.w;
  *(float4*)(p + t*4) = o;
  ushort4 ob; ob.x = f2b(o.x); ob.y = f2b(o.y); ob.z = f2b(o.z); ob.w = f2b(o.w);
  *(ushort4*)(yb + (size_t)row * 1024 + t*4) = ob;
}

// ---------------- launcher ----------------
extern "C" void kernel_launch(void* const* d_in, const int* in_sizes, int n_in,
                              void* d_out, int out_size, void* d_ws, size_t ws_size,
                              hipStream_t stream) {
  const float* x    = (const float*)d_in[0];
  const int*   mask = (const int*)  d_in[1];
  const float* q    = (const float*)d_in[2];
  const float* Wkv  = (const float*)d_in[3];
  const float* lng  = (const float*)d_in[4];
  const float* lnb  = (const float*)d_in[5];
  const float* W1   = (const float*)d_in[6];
  const float* b1   = (const float*)d_in[7];
  const float* W2   = (const float*)d_in[8];
  const float* b2   = (const float*)d_in[9];
  float* out = (float*)d_out;
  char* ws = (char*)d_ws;

  ushort* xb   = (ushort*)(ws);               // 64 MiB; dead after G1
  float*  yf   = (float*) (ws);               // alias: attn out / y
  ushort* kvb  = (ushort*)(ws + 67108864);    // 128 MiB; dead after attn
  ushort* hid  = (ushort*)(ws + 67108864);    // alias: hidden bf16
  ushort* yb   = (ushort*)(ws + 201326592);   // 32 MiB
  ushort* wkvt = (ushort*)(ws + 234881024);   // 4 MiB
  ushort* w1t  = (ushort*)(ws + 239075328);   // 16 MiB (GLU 64-group interleave)
  ushort* w2t  = (ushort*)(ws + 255852544);   // 8 MiB
  ushort* qb   = (ushort*)(ws + 264241152);   // 128 KiB

  conv_x_kernel<<<32768, 256, 0, stream>>>(x, xb);
  conv_q_kernel<<<64, 256, 0, stream>>>(q, qb);
  transpose_w_kernel<<<dim3(64, 32),  256, 0, stream>>>(Wkv, wkvt, 1024, 2048, 0);
  transpose_w_kernel<<<dim3(256, 32), 256, 0, stream>>>(W1,  w1t,  1024, 8192, 1);
  transpose_w_kernel<<<dim3(32, 128), 256, 0, stream>>>(W2,  w2t,  4096, 1024, 0);

  // G1: (32768x1024) @ (1024x2048) -> kv bf16.  grid 128*8 = 1024
  gemm256<0, 1024, 2048><<<1024, 512, 0, stream>>>(xb, wkvt, nullptr, kvb, nullptr, nullptr);
  attn_kernel<<<4096, 256, 0, stream>>>(kvb, qb, mask, yf);
  ln_kernel<<<16384, 256, 0, stream>>>(yf, yb, lng, lnb);
  // G2: (16384x1024) @ (1024x8192) + GLU -> hidden bf16.  grid 64*32 = 2048
  gemm256<1, 1024, 8192><<<2048, 512, 0, stream>>>(yb, w1t, nullptr, hid, b1, nullptr);
  // G3: (16384x4096) @ (4096x1024) + bias + resid -> out.  grid 64*4 = 256
  gemm256<2, 4096, 1024><<<256, 512, 0, stream>>>(hid, w2t, out, nullptr, b2, yf);
}

// Round 3
// 866.238 us; speedup vs baseline: 1.1017x; 1.0218x over previous
//
#include <hip/hip_runtime.h>
#include <stdint.h>
#include <math.h>

// ---------------- constants ----------------
#define SCALE  0.125f

typedef __bf16 bf16;
typedef __bf16 bf16x8 __attribute__((ext_vector_type(8)));
typedef float  f32x4  __attribute__((ext_vector_type(4)));

__device__ __forceinline__ ushort f2b(float f) {
  union { float f; uint32_t u; } v; v.f = f;
  uint32_t u = v.u;
  return (ushort)((u + 0x7fffu + ((u >> 16) & 1u)) >> 16);
}
__device__ __forceinline__ float b2f(ushort s) {
  union { uint32_t u; float f; } v; v.u = ((uint32_t)s) << 16;
  return v.f;
}
__device__ __forceinline__ void g2l16(const ushort* g, ushort* l) {
  __builtin_amdgcn_global_load_lds(
      (const __attribute__((address_space(1))) void*)g,
      (__attribute__((address_space(3))) void*)l, 16, 0, 0);
}
// A&S 7.1.26 erf, |eps| <= 1.5e-7 (far below bf16 rounding). v_rcp + v_exp.
__device__ __forceinline__ float erf_fast(float x) {
  float ax = fabsf(x);
  float t  = __builtin_amdgcn_rcpf(1.0f + 0.3275911f * ax);
  float p  = t * (0.254829592f + t * (-0.284496736f + t * (1.421413741f +
             t * (-1.453152027f + t * 1.061405429f))));
  float e  = __expf(-ax * ax);
  float r  = 1.0f - p * e;
  return copysignf(r, x);
}

// ---------------- conversion kernels ----------------
// x: (S,B,N,D) f32 -> xb: (S,N,B,D) bf16
__global__ __launch_bounds__(256) void conv_x_kernel(const float* __restrict__ x,
                                                     ushort* __restrict__ xb) {
  int idx = blockIdx.x * 256 + threadIdx.x;
  int d4 = idx & 255;
  int n  = (idx >> 8) & 31;
  int b  = (idx >> 13) & 127;
  int s  = idx >> 20;
  float4 v = *(const float4*)(x + (size_t)(((s*128 + b)*32 + n) << 10) + (d4 << 2));
  ushort4 o;
  o.x = f2b(v.x); o.y = f2b(v.y); o.z = f2b(v.z); o.w = f2b(v.w);
  *(ushort4*)(xb + (size_t)(((s*32 + n)*128 + b) << 10) + (d4 << 2)) = o;
}

__global__ __launch_bounds__(256) void conv_q_kernel(const float* __restrict__ q,
                                                     ushort* __restrict__ qb) {
  int idx = blockIdx.x * 256 + threadIdx.x;
  float4 v = *(const float4*)(q + (size_t)idx * 4);
  ushort4 o;
  o.x = f2b(v.x); o.y = f2b(v.y); o.z = f2b(v.z); o.w = f2b(v.w);
  *(ushort4*)(qb + (size_t)idx * 4) = o;
}

// Wt[r][k] = W[k][srccol(r)] (bf16).
// mode 1 = W1 GLU interleave on 64-row groups: group g6 = r>>6, w = r&63:
//   w<32 -> a col g6*32+w ; w>=32 -> gate col 4096 + g6*32 + (w-32).
__global__ __launch_bounds__(256) void transpose_w_kernel(const float* __restrict__ W,
                                                          ushort* __restrict__ Wt,
                                                          int K, int N, int mode) {
  __shared__ float tile[32][33];
  int rt = blockIdx.x, kt = blockIdx.y;
  int r0 = rt * 32;
  int tx = threadIdx.x & 31, ty = threadIdx.x >> 5;
  int src;
  if (mode == 1) {
    int rp = r0 + tx;
    int g6 = rp >> 6, w = rp & 63;
    src = (w < 32) ? (g6*32 + w) : (4096 + g6*32 + (w - 32));
  } else {
    src = r0 + tx;
  }
  for (int i = ty; i < 32; i += 8)
    tile[i][tx] = W[(size_t)(kt*32 + i) * N + src];
  __syncthreads();
  for (int i = ty; i < 32; i += 8)
    Wt[(size_t)(r0 + i) * K + kt*32 + tx] = f2b(tile[tx][i]);
}

// ---------------- main GEMM: 256x256 tile, 4-phase counted-vmcnt pipeline ----
// bf16 A [MxK] x bf16 Bt [NxK]. 512 threads = 8 waves (2M x 4N); per-wave C =
// 128x64 = 8x4 fragments of 16x16 (mfma_f32_16x16x32_bf16). BK=64.
// LDS: A,B double-buffered K-tiles (2 x 32KB each = 128 KiB, 1 block/CU).
// LDS layout per tile: row r = 128B = 8 granules of 16B; granule g of row r at
// slot g^(r&7) (bank-conflict-free ds_read_b128; counter-verified 0 conflicts).
// 16x16x32 fragment: lane (qq=lane>>4, c15=lane&15) reads row c15, k-chunk
// kh*32 + qq*8 -> granule kh*4 + qq.
//
// ROUND-2 LESSON: rigid per-phase {barrier; lgkmcnt(0); MFMA; barrier}
// serializes DS-read vs MFMA (measured MfmaUtil 40%, exactly the serial
// model's ceiling). This version: ONE barrier per phase, NO manual lgkm
// drain before MFMA — compiler emits per-operand lgkmcnt(N) so MFMA issues
// overlap the DS drain; wave skew across the single barrier overlaps pipes
// further. Correctness:
//  - counted-vmcnt asms keep "memory" clobber: ds_reads/stages cannot cross.
//  - empty asm "" memory fence AFTER each publishing barrier: reads cannot
//    hoist into the [vmcnt-asm .. barrier] gap (own-wave-only guarantee).
//  - lgkmcnt(0) pinned once at end of ph3: all tile reads complete before the
//    boundary barrier (WAR vs next tile's staging into this buffer).
//  - empty fence between ph2/ph3 stage groups (and prologue A0,A2|A1,A3):
//    vmcnt(2) must leave exactly {A1,A3} newest in flight.
// Stage issue per tile t (for t+1): ph0:B0,B1  ph1:B2,B3  ph2:A0,A2  ph3:A1,A3.
// Waits: vmcnt(4) end-ph1 (A1,A3 of t landed before ph2 reads them);
//        vmcnt(2) end-ph3 (all of t+1 except A1',A3' landed).
// EPI 0: store bf16 -> outb (stride NCOLS)
// EPI 1: in-register GLU (64-group-interleaved W1t) -> hidden bf16 (stride 4096)
// EPI 2: float out = acc + bias[col] + resid (stride NCOLS)
template <int EPI, int K, int NCOLS>
__global__ __launch_bounds__(512, 2) void gemm256(const ushort* __restrict__ A,
                                                  const ushort* __restrict__ Bt,
                                                  float* __restrict__ outf,
                                                  ushort* __restrict__ outb,
                                                  const float* __restrict__ bias,
                                                  const float* __restrict__ resid) {
  __shared__ ushort As[2][16384];
  __shared__ ushort Bs[2][16384];
  constexpr int NT  = K / 64;
  constexpr int nBn = NCOLS / 256;

  // XCD-aware swizzle (all grids are multiples of 8)
  const int nwg = (int)gridDim.x;
  const int bid = (int)blockIdx.x;
  const int wg  = (bid & 7) * (nwg >> 3) + (bid >> 3);
  const int bm = wg / nBn, bn = wg % nBn;

  const int t = threadIdx.x;
  const int wave = t >> 6, lane = t & 63;
  const int wm = wave >> 2, wn = wave & 3;
  const int c15 = lane & 15, qq = lane >> 4;
  const int swz = c15 & 7;

  // staging: thread t -> row (t>>3) within 64-row call block, slot t&7,
  // source granule (t&7)^(row&7)
  const int rowc = t >> 3;
  const int kg = (t & 7) ^ (rowc & 7);
  const ushort* ag = A  + (size_t)(bm*256 + rowc) * K + kg*8;
  const ushort* bg = Bt + (size_t)(bn*256 + rowc) * K + kg*8;

  f32x4 acc[8][4] = {};

#define LDA_F(buf, mi, kh) \
  (*(const bf16x8*)(&As[buf][(wm*128 + (mi)*16 + c15)*64 + ((((kh)*4 + qq) ^ swz)*8)]))
#define LDB_F(buf, ni, kh) \
  (*(const bf16x8*)(&Bs[buf][(wn*64 + (ni)*16 + c15)*64 + ((((kh)*4 + qq) ^ swz)*8)]))
#define STG_A(c, buf, kt) \
  g2l16(ag + (size_t)(c)*64*K + (size_t)(kt)*64, &As[buf][(c)*4096 + wave*512])
#define STG_B(c, buf, kt) \
  g2l16(bg + (size_t)(c)*64*K + (size_t)(kt)*64, &Bs[buf][(c)*4096 + wave*512])

#define CFENCE asm volatile("" ::: "memory")

#define MFMA8(p, aa, ab, kh) \
  _Pragma("unroll") \
  for (int ni = 0; ni < 4; ++ni) { \
    acc[2*(p)][ni]   = __builtin_amdgcn_mfma_f32_16x16x32_bf16((aa), bfv[ni][(kh)], acc[2*(p)][ni],   0, 0, 0); \
    acc[2*(p)+1][ni] = __builtin_amdgcn_mfma_f32_16x16x32_bf16((ab), bfv[ni][(kh)], acc[2*(p)+1][ni], 0, 0, 0); \
  }

  // prologue: stage tile 0; order [B0..B3, A0, A2 | fence | A1, A3 in flight]
  STG_B(0, 0, 0); STG_B(1, 0, 0); STG_B(2, 0, 0); STG_B(3, 0, 0);
  STG_A(0, 0, 0); STG_A(2, 0, 0);
  CFENCE;
  STG_A(1, 0, 0); STG_A(3, 0, 0);
  asm volatile("s_waitcnt vmcnt(2)" ::: "memory");
  __builtin_amdgcn_s_barrier();
  CFENCE;

#define TILE(kt, cur) { \
    const int nx_ = (cur) ^ 1; \
    const int tn_ = ((kt) + 1 == NT) ? 0 : ((kt) + 1); \
    bf16x8 bfv[4][2]; \
    /* ---- phase 0: quad0 (mi 0,1) + all B; stage B0,B1(next) ---- */ { \
      bf16x8 a00 = LDA_F(cur, 0, 0), a01 = LDA_F(cur, 0, 1); \
      bf16x8 a10 = LDA_F(cur, 1, 0), a11 = LDA_F(cur, 1, 1); \
      _Pragma("unroll") \
      for (int ni = 0; ni < 4; ++ni) { bfv[ni][0] = LDB_F(cur, ni, 0); bfv[ni][1] = LDB_F(cur, ni, 1); } \
      STG_B(0, nx_, tn_); STG_B(1, nx_, tn_); \
      __builtin_amdgcn_s_setprio(1); \
      MFMA8(0, a00, a10, 0); MFMA8(0, a01, a11, 1); \
      __builtin_amdgcn_s_setprio(0); \
      __builtin_amdgcn_s_barrier(); \
    } \
    /* ---- phase 1: quad1 (mi 2,3); stage B2,B3(next); vmcnt(4) ---- */ { \
      bf16x8 a00 = LDA_F(cur, 2, 0), a01 = LDA_F(cur, 2, 1); \
      bf16x8 a10 = LDA_F(cur, 3, 0), a11 = LDA_F(cur, 3, 1); \
      STG_B(2, nx_, tn_); STG_B(3, nx_, tn_); \
      __builtin_amdgcn_s_setprio(1); \
      MFMA8(1, a00, a10, 0); MFMA8(1, a01, a11, 1); \
      __builtin_amdgcn_s_setprio(0); \
      asm volatile("s_waitcnt vmcnt(4)" ::: "memory"); \
      __builtin_amdgcn_s_barrier(); \
      CFENCE; \
    } \
    /* ---- phase 2: quad2 (mi 4,5); stage A0,A2(next) ---- */ { \
      bf16x8 a00 = LDA_F(cur, 4, 0), a01 = LDA_F(cur, 4, 1); \
      bf16x8 a10 = LDA_F(cur, 5, 0), a11 = LDA_F(cur, 5, 1); \
      STG_A(0, nx_, tn_); STG_A(2, nx_, tn_); \
      __builtin_amdgcn_s_setprio(1); \
      MFMA8(2, a00, a10, 0); MFMA8(2, a01, a11, 1); \
      __builtin_amdgcn_s_setprio(0); \
      __builtin_amdgcn_s_barrier(); \
      CFENCE; \
    } \
    /* ---- phase 3: quad3 (mi 6,7); stage A1,A3(next); lgkm0; vmcnt(2) ---- */ { \
      bf16x8 a00 = LDA_F(cur, 6, 0), a01 = LDA_F(cur, 6, 1); \
      bf16x8 a10 = LDA_F(cur, 7, 0), a11 = LDA_F(cur, 7, 1); \
      STG_A(1, nx_, tn_); STG_A(3, nx_, tn_); \
      __builtin_amdgcn_s_setprio(1); \
      MFMA8(3, a00, a10, 0); MFMA8(3, a01, a11, 1); \
      __builtin_amdgcn_s_setprio(0); \
      asm volatile("s_waitcnt lgkmcnt(0)" ::: "memory"); \
      asm volatile("s_waitcnt vmcnt(2)" ::: "memory"); \
      __builtin_amdgcn_s_barrier(); \
      CFENCE; \
    } \
  }

#pragma unroll 1
  for (int kt = 0; kt < NT; kt += 2) {
    TILE(kt, 0);
    TILE(kt + 1, 1);
  }
  // drain wrap-stage DMAs before LDS dealloc at wave exit
  asm volatile("s_waitcnt vmcnt(0)" ::: "memory");

#undef TILE
#undef MFMA8
#undef CFENCE
#undef STG_A
#undef STG_B
#undef LDA_F
#undef LDB_F

  // C/D layout (m89/m91): col = lane&15, row = (lane>>4)*4 + reg
  if (EPI == 0) {
#pragma unroll
    for (int mi = 0; mi < 8; ++mi) {
      int row0 = bm*256 + wm*128 + mi*16 + qq*4;
#pragma unroll
      for (int j = 0; j < 4; ++j) {
#pragma unroll
        for (int ni = 0; ni < 4; ++ni) {
          int col = bn*256 + wn*64 + ni*16 + c15;
          outb[(size_t)(row0 + j) * NCOLS + col] = f2b(acc[mi][ni][j]);
        }
      }
    }
  } else if (EPI == 1) {
    // wave's 64-col slice == one GLU 64-group: g6 = bn*4 + wn.
    // ni 0,1 = 'a' (cols g6*32 + ni*16 + c15); ni 2,3 = gate (same hidden col).
    const int g6 = bn*4 + wn;
    const int hcol0 = g6*32 + c15;
    float ba0 = bias[hcol0],        ba1 = bias[hcol0 + 16];
    float bg0 = bias[4096 + hcol0], bg1 = bias[4096 + hcol0 + 16];
#pragma unroll
    for (int mi = 0; mi < 8; ++mi) {
      int row0 = bm*256 + wm*128 + mi*16 + qq*4;
#pragma unroll
      for (int j = 0; j < 4; ++j) {
        float a0 = acc[mi][0][j] + ba0, g0 = acc[mi][2][j] + bg0;
        float a1 = acc[mi][1][j] + ba1, g1 = acc[mi][3][j] + bg1;
        float ge0 = 0.5f * g0 * (1.0f + erf_fast(g0 * 0.70710678118654752f));
        float ge1 = 0.5f * g1 * (1.0f + erf_fast(g1 * 0.70710678118654752f));
        size_t rb = (size_t)(row0 + j) * 4096;
        outb[rb + hcol0]      = f2b(a0 * ge0);
        outb[rb + hcol0 + 16] = f2b(a1 * ge1);
      }
    }
  } else {
    float bc[4];
#pragma unroll
    for (int ni = 0; ni < 4; ++ni) bc[ni] = bias[bn*256 + wn*64 + ni*16 + c15];
#pragma unroll
    for (int mi = 0; mi < 8; ++mi) {
      int row0 = bm*256 + wm*128 + mi*16 + qq*4;
#pragma unroll
      for (int j = 0; j < 4; ++j) {
#pragma unroll
        for (int ni = 0; ni < 4; ++ni) {
          int col = bn*256 + wn*64 + ni*16 + c15;
          size_t o = (size_t)(row0 + j) * NCOLS + col;
          outf[o] = acc[mi][ni][j] + bc[ni] + resid[o];
        }
      }
    }
  }
}

// ---------------- attention ----------------
__global__ __launch_bounds__(256) void attn_kernel(const ushort* __restrict__ kv,
                                                   const ushort* __restrict__ qb,
                                                   const int* __restrict__ mask,
                                                   float* __restrict__ out) {
  __shared__ ushort Ks[128 * 72];
  __shared__ ushort Vt[64 * 136];
  __shared__ ushort Ps[64 * 136];
  __shared__ float  Mrow[128];

  const int bid = blockIdx.x;
  const int h = bid & 15, n = (bid >> 4) & 31, s = bid >> 9;
  const size_t kvbase = (size_t)((s*32 + n) * 128) * 2048;
  const int t = threadIdx.x, wave = t >> 6, lane = t & 63;
  const int qq = lane >> 4, r = lane & 15;

  if (t < 128) Mrow[t] = (mask[s*128 + t] == 0) ? 1.0f : 0.0f;

  for (int c = t; c < 1024; c += 256) {
    int b = c >> 3, d0 = (c & 7) * 8;
    uint4 v = *(const uint4*)(kv + kvbase + (size_t)b * 2048 + h*64 + d0);
    *(uint4*)(Ks + b*72 + d0) = v;
  }
  {
    int b = t & 127, dh = t >> 7;
    for (int jj = 0; jj < 32; jj += 8) {
      uint4 v = *(const uint4*)(kv + kvbase + (size_t)b * 2048 + 1024 + h*64 + dh*32 + jj);
      const ushort* pv = (const ushort*)&v;
#pragma unroll
      for (int u8 = 0; u8 < 8; u8++)
        Vt[(dh*32 + jj + u8)*136 + b] = pv[u8];
    }
  }
  __syncthreads();

  bf16x8 aq[2];
#pragma unroll
  for (int st = 0; st < 2; st++)
    aq[st] = *(const bf16x8*)(qb + (size_t)(wave*16 + r) * 1024 + h*64 + st*32 + qq*8);
  f32x4 sim[8];
#pragma unroll
  for (int jt = 0; jt < 8; jt++) {
    f32x4 c = {};
#pragma unroll
    for (int st = 0; st < 2; st++) {
      bf16x8 bk = *(const bf16x8*)(Ks + (jt*16 + r)*72 + st*32 + qq*8);
      c = __builtin_amdgcn_mfma_f32_16x16x32_bf16(aq[st], bk, c, 0, 0, 0);
    }
    sim[jt] = c;
  }

#pragma unroll
  for (int jt = 0; jt < 8; jt++) {
    float mflag = Mrow[jt*16 + r];
#pragma unroll
    for (int ii = 0; ii < 4; ii++) {
      float v = sim[jt][ii] * SCALE;
      sim[jt][ii] = (mflag > 0.5f) ? -1e10f : v;
    }
  }
  float mx[4] = {-3.0e38f, -3.0e38f, -3.0e38f, -3.0e38f};
#pragma unroll
  for (int jt = 0; jt < 8; jt++)
#pragma unroll
    for (int ii = 0; ii < 4; ii++) mx[ii] = fmaxf(mx[ii], sim[jt][ii]);
#pragma unroll
  for (int m = 1; m < 16; m <<= 1)
#pragma unroll
    for (int ii = 0; ii < 4; ii++) mx[ii] = fmaxf(mx[ii], __shfl_xor(mx[ii], m));
  float sm[4] = {0.f, 0.f, 0.f, 0.f};
#pragma unroll
  for (int jt = 0; jt < 8; jt++)
#pragma unroll
    for (int ii = 0; ii < 4; ii++) {
      float e = expf(sim[jt][ii] - mx[ii]);
      sim[jt][ii] = e;
      sm[ii] += e;
    }
#pragma unroll
  for (int m = 1; m < 16; m <<= 1)
#pragma unroll
    for (int ii = 0; ii < 4; ii++) sm[ii] += __shfl_xor(sm[ii], m);
#pragma unroll
  for (int ii = 0; ii < 4; ii++) sm[ii] = 1.0f / sm[ii];
#pragma unroll
  for (int jt = 0; jt < 8; jt++)
#pragma unroll
    for (int ii = 0; ii < 4; ii++)
      Ps[(wave*16 + qq*4 + ii)*136 + jt*16 + r] = f2b(sim[jt][ii] * sm[ii]);
  __syncthreads();

  f32x4 o[4] = {};
#pragma unroll
  for (int kst = 0; kst < 4; kst++) {
    bf16x8 ap = *(const bf16x8*)(Ps + (wave*16 + r)*136 + kst*32 + qq*8);
#pragma unroll
    for (int jt2 = 0; jt2 < 4; jt2++) {
      bf16x8 bv = *(const bf16x8*)(Vt + (jt2*16 + r)*136 + kst*32 + qq*8);
      o[jt2] = __builtin_amdgcn_mfma_f32_16x16x32_bf16(ap, bv, o[jt2], 0, 0, 0);
    }
  }
  const size_t orow0 = (size_t)((s*32 + n) * 64);
#pragma unroll
  for (int jt2 = 0; jt2 < 4; jt2++)
#pragma unroll
    for (int ii = 0; ii < 4; ii++) {
      int qr = wave*16 + qq*4 + ii;
      int d  = jt2*16 + r;
      out[(orow0 + qr) * 1024 + h*64 + d] = o[jt2][ii];
    }
}

// ---------------- LayerNorm (in-place) + bf16 copy ----------------
__global__ __launch_bounds__(256) void ln_kernel(float* __restrict__ y,
                                                 ushort* __restrict__ yb,
                                                 const float* __restrict__ g,
                                                 const float* __restrict__ b) {
  __shared__ float r1[4], r2[4];
  const int row = blockIdx.x, t = threadIdx.x;
  const int wave = t >> 6, lane = t & 63;
  float* p = y + (size_t)row * 1024;
  float4 v = *(const float4*)(p + t*4);
  float s1 = v.x + v.y + v.z + v.w;
  float s2 = v.x*v.x + v.y*v.y + v.z*v.z + v.w*v.w;
#pragma unroll
  for (int m = 1; m < 64; m <<= 1) { s1 += __shfl_xor(s1, m); s2 += __shfl_xor(s2, m); }
  if (lane == 0) { r1[wave] = s1; r2[wave] = s2; }
  __syncthreads();
  s1 = r1[0] + r1[1] + r1[2] + r1[3];
  s2 = r2[0] + r2[1] + r2[2] + r2[3];
  float mu  = s1 * (1.0f/1024.0f);
  float var = s2 * (1.0f/1024.0f) - mu*mu;
  float inv = rsqrtf(var + 1e-5f);
  float4 gg = *(const float4*)(g + t*4);
  float4 bb = *(const float4*)(b + t*4);
  float4 o;
  o.x = (v.x - mu)*inv*gg.x + bb.x;
  o.y = (v.y - mu)*inv*gg.y + bb.y;
  o.z = (v.z - mu)*inv*gg.z + bb.z;
  o.w = (v.w - mu)*inv*gg.w + bb.w;
  *(float4*)(p + t*4) = o;
  ushort4 ob; ob.x = f2b(o.x); ob.y = f2b(o.y); ob.z = f2b(o.z); ob.w = f2b(o.w);
  *(ushort4*)(yb + (size_t)row * 1024 + t*4) = ob;
}

// ---------------- launcher ----------------
extern "C" void kernel_launch(void* const* d_in, const int* in_sizes, int n_in,
                              void* d_out, int out_size, void* d_ws, size_t ws_size,
                              hipStream_t stream) {
  const float* x    = (const float*)d_in[0];
  const int*   mask = (const int*)  d_in[1];
  const float* q    = (const float*)d_in[2];
  const float* Wkv  = (const float*)d_in[3];
  const float* lng  = (const float*)d_in[4];
  const float* lnb  = (const float*)d_in[5];
  const float* W1   = (const float*)d_in[6];
  const float* b1   = (const float*)d_in[7];
  const float* W2   = (const float*)d_in[8];
  const float* b2   = (const float*)d_in[9];
  float* out = (float*)d_out;
  char* ws = (char*)d_ws;

  ushort* xb   = (ushort*)(ws);               // 64 MiB; dead after G1
  float*  yf   = (float*) (ws);               // alias: attn out / y
  ushort* kvb  = (ushort*)(ws + 67108864);    // 128 MiB; dead after attn
  ushort* hid  = (ushort*)(ws + 67108864);    // alias: hidden bf16
  ushort* yb   = (ushort*)(ws + 201326592);   // 32 MiB
  ushort* wkvt = (ushort*)(ws + 234881024);   // 4 MiB
  ushort* w1t  = (ushort*)(ws + 239075328);   // 16 MiB (GLU 64-group interleave)
  ushort* w2t  = (ushort*)(ws + 255852544);   // 8 MiB
  ushort* qb   = (ushort*)(ws + 264241152);   // 128 KiB

  conv_x_kernel<<<32768, 256, 0, stream>>>(x, xb);
  conv_q_kernel<<<64, 256, 0, stream>>>(q, qb);
  transpose_w_kernel<<<dim3(64, 32),  256, 0, stream>>>(Wkv, wkvt, 1024, 2048, 0);
  transpose_w_kernel<<<dim3(256, 32), 256, 0, stream>>>(W1,  w1t,  1024, 8192, 1);
  transpose_w_kernel<<<dim3(32, 128), 256, 0, stream>>>(W2,  w2t,  4096, 1024, 0);

  // G1: (32768x1024) @ (1024x2048) -> kv bf16.  grid 128*8 = 1024
  gemm256<0, 1024, 2048><<<1024, 512, 0, stream>>>(xb, wkvt, nullptr, kvb, nullptr, nullptr);
  attn_kernel<<<4096, 256, 0, stream>>>(kvb, qb, mask, yf);
  ln_kernel<<<16384, 256, 0, stream>>>(yf, yb, lng, lnb);
  // G2: (16384x1024) @ (1024x8192) + GLU -> hidden bf16.  grid 64*32 = 2048
  gemm256<1, 1024, 8192><<<2048, 512, 0, stream>>>(yb, w1t, nullptr, hid, b1, nullptr);
  // G3: (16384x4096) @ (4096x1024) + bias + resid -> out.  grid 64*4 = 256
  gemm256<2, 4096, 1024><<<256, 512, 0, stream>>>(hid, w2t, out, nullptr, b2, yf);
}